// Round 1
// baseline (46.667 us; speedup 1.0000x reference)
//
#include <hip/hip_runtime.h>
#include <hip/hip_bf16.h>

#define NB 64
#define ND 64
#define NQ 2048
#define NS 2048
#define QBLK 256
#define SBLK 64
#define QPB 8   // q-blocks per batch = NQ/QBLK

typedef float f32x4 __attribute__((ext_vector_type(4)));
typedef short bf16x8 __attribute__((ext_vector_type(8)));
typedef int i32x4 __attribute__((ext_vector_type(4)));

__device__ inline unsigned short f2bf(float v) {
  union { float f; unsigned u; } x; x.f = v;
  unsigned r = x.u + 0x7fffu + ((x.u >> 16) & 1u);  // RNE
  return (unsigned short)(r >> 16);
}

// Block: one batch b, QBLK=256 q-rows. 4 waves x 64 q-rows.
// A (Q^T tile) in registers for entire s-loop; S staged per 64-col tile in LDS
// as bf16 [s][d] with 16B-slot XOR swizzle (slot ^= s&7).
__global__ __launch_bounds__(256, 2) void bmd_main(
    const float* __restrict__ Q, const float* __restrict__ S,
    float* __restrict__ part) {
  const int bid = blockIdx.x;
  const int b  = bid & (NB - 1);   // id%8 == b%8 -> all q-blocks of b on one XCD
  const int qb = bid >> 6;
  const int q0 = qb * QBLK;
  const int tid = threadIdx.x;
  const int lane = tid & 63;
  const int w = tid >> 6;

  __shared__ i32x4 sT4[SBLK * 8];   // 64 rows x 128B (8 slots x 16B), swizzled
  __shared__ float wsum[4];
  char* sT = (char*)sT4;

  const float* Qb = Q + (size_t)b * ND * NQ;
  const float* Sb = S + (size_t)b * ND * NS;

  // ---- A fragments: row = lane&15 (q), k = (lane>>4)*8+e (d) ----
  bf16x8 afrag[4][2];   // [mf (16 q-rows each)][ks (k-step of 32)]
  {
    const int qrow = q0 + w * 64 + (lane & 15);
    const int dbase = (lane >> 4) * 8;
    for (int mf = 0; mf < 4; ++mf)
      for (int ks = 0; ks < 2; ++ks) {
        const int d0 = ks * 32 + dbase;
        bf16x8 f;
        #pragma unroll
        for (int e = 0; e < 8; ++e)
          f[e] = (short)f2bf(Qb[(size_t)(d0 + e) * NQ + (qrow + mf * 16)]);
        afrag[mf][ks] = f;
      }
  }

  f32x4 rmax[4];
  for (int mf = 0; mf < 4; ++mf)
    rmax[mf] = f32x4{-INFINITY, -INFINITY, -INFINITY, -INFINITY};

  // staging assignment: thread -> (d-block 0..7, s-col), lanes spread slots
  const int dbq = (tid >> 3) & 7;
  const int sl0 = (tid & 7) + ((tid >> 6) << 3);

  for (int s0 = 0; s0 < NS; s0 += SBLK) {
    __syncthreads();
    #pragma unroll
    for (int i = 0; i < 2; ++i) {
      const int sl = sl0 + i * 32;
      const float* src = Sb + (size_t)dbq * 8 * NS + (s0 + sl);
      bf16x8 pk;
      #pragma unroll
      for (int e = 0; e < 8; ++e) pk[e] = (short)f2bf(src[(size_t)e * NS]);
      const int byt = sl * 128 + ((dbq ^ (sl & 7)) << 4);
      *reinterpret_cast<bf16x8*>(sT + byt) = pk;
    }
    __syncthreads();

    #pragma unroll
    for (int nf = 0; nf < 4; ++nf) {
      const int scol = nf * 16 + (lane & 15);
      bf16x8 bfr[2];
      #pragma unroll
      for (int ks = 0; ks < 2; ++ks) {
        const int slot = (ks * 4 + (lane >> 4)) ^ (scol & 7);
        bfr[ks] = *reinterpret_cast<const bf16x8*>(sT + scol * 128 + (slot << 4));
      }
      #pragma unroll
      for (int mf = 0; mf < 4; ++mf) {
        f32x4 acc = {0.f, 0.f, 0.f, 0.f};
        acc = __builtin_amdgcn_mfma_f32_16x16x32_bf16(afrag[mf][0], bfr[0], acc, 0, 0, 0);
        acc = __builtin_amdgcn_mfma_f32_16x16x32_bf16(afrag[mf][1], bfr[1], acc, 0, 0, 0);
        #pragma unroll
        for (int j = 0; j < 4; ++j) rmax[mf][j] = fmaxf(rmax[mf][j], acc[j]);
      }
    }
  }

  // ---- epilogue: max across the 16 col-lanes, then sum the q-rows ----
  float qsum = 0.f;
  for (int mf = 0; mf < 4; ++mf)
    for (int j = 0; j < 4; ++j) {
      float v = rmax[mf][j];
      v = fmaxf(v, __shfl_xor(v, 1));
      v = fmaxf(v, __shfl_xor(v, 2));
      v = fmaxf(v, __shfl_xor(v, 4));
      v = fmaxf(v, __shfl_xor(v, 8));
      qsum += v;    // row-max for row (lane>>4)*4 + j (+16*mf)
    }
  qsum += __shfl_xor(qsum, 16);   // sum across the 4 row-groups
  qsum += __shfl_xor(qsum, 32);
  if (lane == 0) wsum[w] = qsum;
  __syncthreads();
  if (tid == 0)
    part[b * QPB + qb] = wsum[0] + wsum[1] + wsum[2] + wsum[3];
}

__global__ void bmd_reduce(const float* __restrict__ part, float* __restrict__ out) {
  const int b = threadIdx.x;   // 64 threads
  float s = 0.f;
  for (int i = 0; i < QPB; ++i) s += part[b * QPB + i];
  out[b] = s * (1.0f / NQ);
}

extern "C" void kernel_launch(void* const* d_in, const int* in_sizes, int n_in,
                              void* d_out, int out_size, void* d_ws, size_t ws_size,
                              hipStream_t stream) {
  const float* Q = (const float*)d_in[0];
  const float* S = (const float*)d_in[1];
  float* out = (float*)d_out;
  float* part = (float*)d_ws;   // 512 floats
  bmd_main<<<dim3(NB * QPB), dim3(256), 0, stream>>>(Q, S, part);
  bmd_reduce<<<dim3(1), dim3(NB), 0, stream>>>(part, out);
}

// Round 2
// 45.836 us; speedup vs baseline: 1.0181x; 1.0181x over previous
//
#include <hip/hip_runtime.h>

#define NB 64
#define ND 64
#define NQ 2048
#define NS 2048
#define QBLK 256
#define SBLK 64
#define QPB 8              // q-blocks per batch
#define NSPLIT 2           // s-range splits per (b,qb)
#define NSS (NS / NSPLIT)  // 1024 s-cols per block
#define NT (NSS / SBLK)    // 16 tiles per block

typedef float f32x4 __attribute__((ext_vector_type(4)));
typedef short bf16x8 __attribute__((ext_vector_type(8)));

__device__ inline unsigned short f2bf(float v) {
  union { float f; unsigned u; } x; x.f = v;
  unsigned r = x.u + 0x7fffu + ((x.u >> 16) & 1u);  // RNE
  return (unsigned short)(r >> 16);
}

// bid = ss*512 + qb*64 + b  (b in low bits -> all blocks of batch b on XCD b%8)
// Block: batch b, 256 q-rows, s-cols [ss*1024, ss*1024+1024). 4 waves x 64 q.
// A (Q^T) in registers for the whole s-loop. S staged per 64-col tile in LDS
// bf16 [s][d], 16B-slot XOR swizzle; double-buffered with register prefetch,
// ONE barrier per tile.
__global__ __launch_bounds__(256, 4) void bmd_main(
    const float* __restrict__ Q, const float* __restrict__ S,
    float* __restrict__ part) {
  const int bid = blockIdx.x;
  const int b  = bid & (NB - 1);
  const int qb = (bid >> 6) & (QPB - 1);
  const int ss = bid >> 9;
  const int q0 = qb * QBLK;
  const int sbase = ss * NSS;
  const int tid = threadIdx.x;
  const int lane = tid & 63;
  const int w = tid >> 6;

  __shared__ char sT[2][SBLK * 128];

  const float* Qb = Q + (size_t)b * ND * NQ;
  const float* Sb = S + (size_t)b * ND * NS;

  // ---- A fragments: row = lane&15 (q), k = (lane>>4)*8+e (d) ----
  bf16x8 afrag[4][2];  // [mf: 16 q-rows each][ks: k-step of 32]
  {
    const int qrow = q0 + w * 64 + (lane & 15);
    const int dbase = (lane >> 4) * 8;
    for (int mf = 0; mf < 4; ++mf)
      for (int ks = 0; ks < 2; ++ks) {
        const int d0 = ks * 32 + dbase;
        bf16x8 f;
        #pragma unroll
        for (int e = 0; e < 8; ++e)
          f[e] = (short)f2bf(Qb[(size_t)(d0 + e) * NQ + (qrow + mf * 16)]);
        afrag[mf][ks] = f;
      }
  }

  f32x4 rmax[4];
  #pragma unroll
  for (int mf = 0; mf < 4; ++mf)
    rmax[mf] = f32x4{-INFINITY, -INFINITY, -INFINITY, -INFINITY};

  // staging assignment: thread -> (d-block dbq, s-cols sl, sl+32)
  const int dbq = (tid >> 3) & 7;
  const int sl0 = (tid & 7) + (w << 3);
  const float* stage_src = Sb + (size_t)dbq * 8 * NS + sbase;
  int sl[2], byt[2];
  #pragma unroll
  for (int i = 0; i < 2; ++i) {
    sl[i] = sl0 + i * 32;
    byt[i] = sl[i] * 128 + ((dbq ^ (sl[i] & 7)) << 4);
  }

  // ---- stage tile 0 ----
  #pragma unroll
  for (int i = 0; i < 2; ++i) {
    const float* src = stage_src + sl[i];
    bf16x8 pk;
    #pragma unroll
    for (int e = 0; e < 8; ++e) pk[e] = (short)f2bf(src[(size_t)e * NS]);
    *reinterpret_cast<bf16x8*>(sT[0] + byt[i]) = pk;
  }
  __syncthreads();

  int cur = 0;
  for (int t = 0; t < NT; ++t) {
    // issue next tile's global loads (raw f32) -- latency hides under MFMAs
    float pf[2][8];
    const bool has_next = (t + 1 < NT);
    if (has_next) {
      const float* src = stage_src + (t + 1) * SBLK;
      #pragma unroll
      for (int i = 0; i < 2; ++i)
        #pragma unroll
        for (int e = 0; e < 8; ++e)
          pf[i][e] = src[sl[i] + (size_t)e * NS];
    }

    // ---- compute tile t from sT[cur] ----
    #pragma unroll
    for (int nf = 0; nf < 4; ++nf) {
      const int scol = nf * 16 + (lane & 15);
      bf16x8 bfr[2];
      #pragma unroll
      for (int ks = 0; ks < 2; ++ks) {
        const int slot = (ks * 4 + (lane >> 4)) ^ (scol & 7);
        bfr[ks] = *reinterpret_cast<const bf16x8*>(sT[cur] + scol * 128 + (slot << 4));
      }
      #pragma unroll
      for (int mf = 0; mf < 4; ++mf) {
        f32x4 acc = {0.f, 0.f, 0.f, 0.f};
        acc = __builtin_amdgcn_mfma_f32_16x16x32_bf16(afrag[mf][0], bfr[0], acc, 0, 0, 0);
        acc = __builtin_amdgcn_mfma_f32_16x16x32_bf16(afrag[mf][1], bfr[1], acc, 0, 0, 0);
        #pragma unroll
        for (int j = 0; j < 4; ++j) rmax[mf][j] = fmaxf(rmax[mf][j], acc[j]);
      }
    }

    // ---- convert + write tile t+1 into the other buffer ----
    if (has_next) {
      #pragma unroll
      for (int i = 0; i < 2; ++i) {
        bf16x8 pk;
        #pragma unroll
        for (int e = 0; e < 8; ++e) pk[e] = (short)f2bf(pf[i][e]);
        *reinterpret_cast<bf16x8*>(sT[cur ^ 1] + byt[i]) = pk;
      }
    }
    __syncthreads();
    cur ^= 1;
  }

  // ---- epilogue: max across the 16 col-lanes -> per-row max to ws ----
  float* rowp = part + (size_t)bid * QBLK + w * 64;
  #pragma unroll
  for (int mf = 0; mf < 4; ++mf) {
    #pragma unroll
    for (int j = 0; j < 4; ++j) {
      float v = rmax[mf][j];
      v = fmaxf(v, __shfl_xor(v, 1));
      v = fmaxf(v, __shfl_xor(v, 2));
      v = fmaxf(v, __shfl_xor(v, 4));
      v = fmaxf(v, __shfl_xor(v, 8));
      if ((lane & 15) == 0)
        rowp[mf * 16 + (lane >> 4) * 4 + j] = v;  // row-max for this q-row
    }
  }
}

// out[b] = mean_q max_ss rowmax -- 64 blocks x 256 threads
__global__ void bmd_reduce(const float* __restrict__ part, float* __restrict__ out) {
  const int b = blockIdx.x;
  const int tid = threadIdx.x;
  __shared__ float ws4[4];
  float sum = 0.f;
  for (int qb = 0; qb < QPB; ++qb) {
    const float v0 = part[((size_t)(qb * NB + b)) * QBLK + tid];
    const float v1 = part[((size_t)(NB * QPB + qb * NB + b)) * QBLK + tid];
    sum += fmaxf(v0, v1);
  }
  #pragma unroll
  for (int o = 1; o < 64; o <<= 1) sum += __shfl_xor(sum, o);
  if ((tid & 63) == 0) ws4[tid >> 6] = sum;
  __syncthreads();
  if (tid == 0) out[b] = (ws4[0] + ws4[1] + ws4[2] + ws4[3]) * (1.0f / NQ);
}

extern "C" void kernel_launch(void* const* d_in, const int* in_sizes, int n_in,
                              void* d_out, int out_size, void* d_ws, size_t ws_size,
                              hipStream_t stream) {
  const float* Q = (const float*)d_in[0];
  const float* S = (const float*)d_in[1];
  float* out = (float*)d_out;
  float* part = (float*)d_ws;  // NB*QPB*NSPLIT*QBLK = 256K floats = 1 MB
  bmd_main<<<dim3(NB * QPB * NSPLIT), dim3(256), 0, stream>>>(Q, S, part);
  bmd_reduce<<<dim3(NB), dim3(256), 0, stream>>>(part, out);
}